// Round 2
// baseline (90.332 us; speedup 1.0000x reference)
//
#include <hip/hip_runtime.h>

// IMPACT modality argmin, item-sorted for L2 locality.
//
// Pipeline (all on `stream`):
//   1. memsetAsync hist=0
//   2. hist_kernel:    hist[item] += 1 over all queries
//   3. scan_kernel:    cursor = exclusive prefix sum of hist (1 block)
//   4. scatter_kernel: perm[atomicAdd(cursor[item])] = query  (groups by item)
//   5. main kernel:    process queries in perm order -> same-item queries
//                      adjacent -> item rows served from L1/L2, not HBM.
//
// Distances accumulated in f64 of exact f32 diffs so the argmin matches the
// f32 numpy reference ordering (proven absmax 0.0 in round 1).

#define M_TOT 14
#define CDIM 128

__global__ void hist_kernel(const int* __restrict__ item_ids,
                            int* __restrict__ hist, int B) {
    int i = blockIdx.x * blockDim.x + threadIdx.x;
    if (i < B) atomicAdd(&hist[item_ids[i]], 1);
}

__global__ __launch_bounds__(1024) void scan_kernel(const int* __restrict__ hist,
                                                    int* __restrict__ cursor, int n) {
    __shared__ int partial[1024];
    int tid = threadIdx.x;
    int ch = (n + 1023) >> 10;        // elements per thread
    int base = tid * ch;
    int s = 0;
    for (int j = 0; j < ch; ++j) {
        int k = base + j;
        if (k < n) s += hist[k];
    }
    partial[tid] = s;
    __syncthreads();
    // Hillis-Steele inclusive scan over the 1024 partials
    for (int off = 1; off < 1024; off <<= 1) {
        int v = (tid >= off) ? partial[tid - off] : 0;
        __syncthreads();
        partial[tid] += v;
        __syncthreads();
    }
    int run = (tid > 0) ? partial[tid - 1] : 0;   // exclusive prefix of my chunk
    for (int j = 0; j < ch; ++j) {
        int k = base + j;
        if (k < n) { cursor[k] = run; run += hist[k]; }
    }
}

__global__ void scatter_kernel(const int* __restrict__ item_ids,
                               int* __restrict__ cursor,
                               int* __restrict__ perm, int B) {
    int i = blockIdx.x * blockDim.x + threadIdx.x;
    if (i < B) {
        int pos = atomicAdd(&cursor[item_ids[i]], 1);
        perm[pos] = i;
    }
}

__global__ __launch_bounds__(256) void impact_argmin_kernel(
    const int* __restrict__ user_ids,
    const int* __restrict__ item_ids,
    const float* __restrict__ users_emb,   // [USER_N, 128]
    const float* __restrict__ item_emb,    // [ITEM_N*14, 128]
    const int* __restrict__ nb_mod,        // [ITEM_N]
    const int* __restrict__ perm,          // may be null (unsorted fallback)
    float* __restrict__ out,
    int B)
{
    int tid = blockIdx.x * blockDim.x + threadIdx.x;
    int i = tid >> 4;          // one query per 16-lane group
    int l = tid & 15;
    if (i >= B) return;
    int q = perm ? perm[i] : i;

    int uid = user_ids[q];
    int iid = item_ids[q];
    int nb  = nb_mod[iid];     // in [2, 12]; valid modality cols are 1..nb

    // user row: 32 float4s, lanes 0..15 read two coalesced float4s each
    const float4* urow = (const float4*)(users_emb + (size_t)uid * CDIM);
    float4 u0 = urow[l];
    float4 u1 = urow[l + 16];

    double best = 1e300;
    int bidx = 1;

    const float4* ibase =
        (const float4*)(item_emb + ((size_t)iid * M_TOT + 1) * CDIM);

    for (int m = 1; m <= nb; ++m) {
        const float4* vrow = ibase + (size_t)(m - 1) * (CDIM / 4);
        float4 v0 = vrow[l];
        float4 v1 = vrow[l + 16];

        float d;
        double s = 0.0;
        d = u0.x - v0.x; s += (double)d * d;
        d = u0.y - v0.y; s += (double)d * d;
        d = u0.z - v0.z; s += (double)d * d;
        d = u0.w - v0.w; s += (double)d * d;
        d = u1.x - v1.x; s += (double)d * d;
        d = u1.y - v1.y; s += (double)d * d;
        d = u1.z - v1.z; s += (double)d * d;
        d = u1.w - v1.w; s += (double)d * d;

        // 16-lane butterfly reduce (xor masks < 16 stay within the group)
        s += __shfl_xor(s, 1);
        s += __shfl_xor(s, 2);
        s += __shfl_xor(s, 4);
        s += __shfl_xor(s, 8);

        // ascending m + strict '<' == argmin first-occurrence semantics
        if (s < best) { best = s; bidx = m; }
    }

    if (l == 0)
        out[q] = (float)(bidx - 1) / (float)(nb - 1) + 1.0f;
}

extern "C" void kernel_launch(void* const* d_in, const int* in_sizes, int n_in,
                              void* d_out, int out_size, void* d_ws, size_t ws_size,
                              hipStream_t stream) {
    // inputs: 0 user_ids, 1 item_ids, 2 concept_ids (unused),
    //         3 users_emb_weight, 4 item_resp_emb_weight,
    //         5 mask (unused; nb_modalities carries the same info), 6 nb_modalities
    const int*   user_ids  = (const int*)d_in[0];
    const int*   item_ids  = (const int*)d_in[1];
    const float* users_emb = (const float*)d_in[3];
    const float* item_emb  = (const float*)d_in[4];
    const int*   nb_mod    = (const int*)d_in[6];
    float* out = (float*)d_out;

    int B = in_sizes[0];
    int n_items = in_sizes[6];

    // ws layout: hist[n_items] | cursor[n_items] | perm[B]
    size_t need = ((size_t)n_items * 2 + (size_t)B) * sizeof(int);
    int* perm = nullptr;

    if (ws_size >= need) {
        int* hist   = (int*)d_ws;
        int* cursor = hist + n_items;
        perm        = cursor + n_items;

        hipMemsetAsync(hist, 0, (size_t)n_items * sizeof(int), stream);
        hist_kernel<<<(B + 255) / 256, 256, 0, stream>>>(item_ids, hist, B);
        scan_kernel<<<1, 1024, 0, stream>>>(hist, cursor, n_items);
        scatter_kernel<<<(B + 255) / 256, 256, 0, stream>>>(item_ids, cursor, perm, B);
    }

    int grid = (B + 15) / 16;   // 16 queries per 256-thread block
    impact_argmin_kernel<<<grid, 256, 0, stream>>>(
        user_ids, item_ids, users_emb, item_emb, nb_mod, perm, out, B);
}